// Round 19
// baseline (233.527 us; speedup 1.0000x reference)
//
#include <hip/hip_runtime.h>

typedef unsigned int u32;
typedef unsigned long long u64;

#define NPTS   1000000
#define KSTEPS 32
#define NF     8
#define IMG_H  1024
#define IMG_W  1024
#define FID    1000
#define HW     (IMG_H * IMG_W)
#define NB     3907            // ceil(NPTS/256)
#define NBKT   512             // bucket = pixel >> 11  (2 image rows)
#define BKTPX  2048            // pixels per bucket
#define SEGW   (256 * KSTEPS)  // 8192 words per block-major segment
#define PARTCH 1016            // max chunks = 512 + 504
#define HTILES (2 * PARTCH)    // half-tiles (ch01 and ch23 per chunk)
#define HTW    4096            // u32 words per half-tile (BKTPX u64)
#define PARTA_T 976            // half-tiles aliased over counts+lpre (16MB)
#define K5G2   2048            // accumulate grid (>= HTILES)
#define MSTG   512             // meta staging span (g's per stage)
#define FPSCALE 4194304.0f     // 2^22 fixed point; capacity 1024 > max sum 488
#define FPINV   (1.0f / 4194304.0f)

// Extract step K's function index from packed nibble words p0..p3.
#define GETIDX(K)                                                              \
    ((int)(((((K) >> 3) == 0 ? p0 : ((K) >> 3) == 1 ? p1                       \
            : ((K) >> 3) == 2 ? p2 : p3) >> (((K) & 7) * 4)) & 7u))

// One chaos-game step, numpy-exact (no FMA contraction). Scalar LDS table
// reads: 8 distinct rows max -> broadcast/2-way aliasing (free on CDNA4).
#define FLAME_STEP(IDX, K)                                                     \
  {                                                                            \
    const float a00 = s_tab[(IDX)*8+0], a01 = s_tab[(IDX)*8+1];                \
    const float a10 = s_tab[(IDX)*8+2], a11 = s_tab[(IDX)*8+3];                \
    const float b0  = s_tab[(IDX)*8+4], b1  = s_tab[(IDX)*8+5];                \
    const float fc  = s_tab[(IDX)*8+6];                                        \
    const float nx = __fadd_rn(__fadd_rn(__fmul_rn(a00,x),__fmul_rn(a01,y)),b0);\
    const float ny = __fadd_rn(__fadd_rn(__fmul_rn(a10,x),__fmul_rn(a11,y)),b1);\
    x = nx; y = ny;                                                            \
    c = __fmul_rn(__fadd_rn(c, fc), 0.5f);                                     \
    xb = (int)__fmul_rn(__fsub_rn(x, minx), rx);                               \
    yb = (int)__fmul_rn(__fsub_rn(y, miny), ry);                               \
    inb = (xb >= 0) & (xb < IMG_W) & (yb >= 0) & (yb < IMG_H) & ((K) >= skipk);\
  }

#define LOAD_TABLES()                                                          \
    if (threadIdx.x < NF) {                                                    \
        const int f = threadIdx.x;                                             \
        s_tab[f*8+0] = Amat[f*4+0]; s_tab[f*8+1] = Amat[f*4+1];                \
        s_tab[f*8+2] = Amat[f*4+2]; s_tab[f*8+3] = Amat[f*4+3];                \
        s_tab[f*8+4] = bvec[f*2+0]; s_tab[f*8+5] = bvec[f*2+1];                \
        s_tab[f*8+6] = fcolor[f];   s_tab[f*8+7] = 0.0f;                       \
    }

// Half-tile pointer: h in [0, HTILES); first PARTA_T alias counts+lpre.
__device__ __forceinline__ u32* htile_ptr(u32* partA, u32* partB, u32 h) {
    return (h < PARTA_T) ? partA + (size_t)h * HTW
                         : partB + (size_t)(h - PARTA_T) * HTW;
}
__device__ __forceinline__ const u32* htile_ptr_c(const u32* partA,
                                                  const u32* partB, u32 h) {
    return (h < PARTA_T) ? partA + (size_t)h * HTW
                         : partB + (size_t)(h - PARTA_T) * HTW;
}

// ---------------------------------------------------------------------------
// K1: the ONLY flame pass (unchanged from round 11).
// ---------------------------------------------------------------------------
__global__ __launch_bounds__(256) void k_flame(
    const float* __restrict__ Amat, const float* __restrict__ bvec,
    const float* __restrict__ fcolor,
    const float* __restrict__ xy0, const float* __restrict__ c0,
    const float* __restrict__ minv, const float* __restrict__ rangev,
    const int* __restrict__ fn_idx, const int* __restrict__ skipk_ptr,
    u32* __restrict__ counts, u32* __restrict__ lpre,
    u32* __restrict__ blockmajor)
{
    __shared__ u32 s_rec[SEGW];          // 32 KB
    __shared__ u32 s_cnt[NBKT];          // counts, then cursors
    __shared__ u32 s_scan[256];
    __shared__ float s_tab[NF * 8];
    const int tid = threadIdx.x;

    s_cnt[tid] = 0u; s_cnt[tid + 256] = 0u;
    LOAD_TABLES();
    __syncthreads();

    const int i = blockIdx.x * 256 + tid;
    u32 rec[KSTEPS];

    if (i < NPTS) {
        u32 p0 = 0, p1 = 0, p2 = 0, p3 = 0;
        #pragma unroll
        for (int k = 0; k < 8; ++k)
            p0 |= ((u32)fn_idx[(size_t)k * NPTS + i] & 7u) << (k * 4);
        #pragma unroll
        for (int k = 0; k < 8; ++k)
            p1 |= ((u32)fn_idx[(size_t)(k + 8) * NPTS + i] & 7u) << (k * 4);
        #pragma unroll
        for (int k = 0; k < 8; ++k)
            p2 |= ((u32)fn_idx[(size_t)(k + 16) * NPTS + i] & 7u) << (k * 4);
        #pragma unroll
        for (int k = 0; k < 8; ++k)
            p3 |= ((u32)fn_idx[(size_t)(k + 24) * NPTS + i] & 7u) << (k * 4);

        const int   skipk = skipk_ptr[0];
        const float minx = minv[0], miny = minv[1];
        const float rx = rangev[0], ry = rangev[1];
        const float2 xyv = ((const float2*)xy0)[i];
        float x = xyv.x, y = xyv.y, c = c0[i];
        #pragma unroll
        for (int k = 0; k < KSTEPS; ++k) {
            const int idx = GETIDX(k);
            int xb, yb; bool inb;
            FLAME_STEP(idx, k);
            u32 r = 0xFFFFFFFFu;
            if (inb) {
                int pi = (int)__fadd_rn(__fmul_rn(c, 999.0f), 0.0005f);
                pi = min(max(pi, 0), FID - 1);
                r = (((u32)(xb << 10 | yb)) << 10) | (u32)pi;
                atomicAdd(&s_cnt[r >> 21], 1u);
            }
            rec[k] = r;
        }
    }
    __syncthreads();

    // Local exclusive scan over 512 bucket counts (2 per thread).
    const u32 cA = s_cnt[2 * tid], cB = s_cnt[2 * tid + 1];
    const u32 psum = cA + cB;
    s_scan[tid] = psum; __syncthreads();
    #pragma unroll
    for (int o = 1; o < 256; o <<= 1) {
        u32 t = (tid >= o) ? s_scan[tid - o] : 0u;
        __syncthreads();
        s_scan[tid] += t;
        __syncthreads();
    }
    const u32 excl = s_scan[tid] - psum;

    // Cursors in LDS; per-(block,bucket) meta to global (coalesced).
    s_cnt[2 * tid] = excl; s_cnt[2 * tid + 1] = excl + cA;
    const size_t g0 = (size_t)blockIdx.x * NBKT;
    lpre[g0 + 2 * tid] = excl;  lpre[g0 + 2 * tid + 1] = excl + cA;
    counts[g0 + 2 * tid] = cA;  counts[g0 + 2 * tid + 1] = cB;
    __syncthreads();

    // Re-scatter rec[] from VGPRs into LDS, bucket-sorted.
    if (i < NPTS) {
        #pragma unroll
        for (int k = 0; k < KSTEPS; ++k) {
            const u32 r = rec[k];
            if (r != 0xFFFFFFFFu) {
                const u32 pos = atomicAdd(&s_cnt[r >> 21], 1u);
                s_rec[pos] = r;
            }
        }
    }
    __syncthreads();

    // Dense copy to block-major segment (uint4).
    const u32 vt = s_scan[255];          // total valid records this block
    u32* dst = blockmajor + (size_t)blockIdx.x * SEGW;
    const u32 nv4 = vt >> 2;
    for (u32 q = tid; q < nv4; q += 256)
        ((uint4*)dst)[q] = make_uint4(s_rec[4*q], s_rec[4*q+1],
                                      s_rec[4*q+2], s_rec[4*q+3]);
    for (u32 j = (nv4 << 2) + tid; j < vt; j += 256) dst[j] = s_rec[j];
}

// ---------------------------------------------------------------------------
// K2: transpose meta to bucket-major + per-bucket totals. grid = NBKT.
// ---------------------------------------------------------------------------
__global__ __launch_bounds__(256) void k_transpose(
    const u32* __restrict__ counts, const u32* __restrict__ lpre,
    u32* __restrict__ counts_t, u32* __restrict__ lpre_t,
    u32* __restrict__ totals)
{
    const int b = blockIdx.x, tid = threadIdx.x;
    u32 s = 0;
    for (int row = tid; row < NB; row += 256) {
        const u32 cv = counts[(size_t)row * NBKT + b];
        const u32 lv = lpre[(size_t)row * NBKT + b];
        counts_t[(size_t)b * NB + row] = cv;
        lpre_t[(size_t)b * NB + row] = lv;
        s += cv;
    }
    __shared__ u32 red[256];
    red[tid] = s; __syncthreads();
    #pragma unroll
    for (int o = 128; o; o >>= 1) {
        if (tid < o) red[tid] += red[tid + o];
        __syncthreads();
    }
    if (tid == 0) totals[b] = red[0];
}

// ---------------------------------------------------------------------------
// K3: chunk counts m[b], wstart scan, fixed-point palette. 1 wg x 512.
// ---------------------------------------------------------------------------
__global__ __launch_bounds__(512) void k_meta(
    const float* __restrict__ palette,
    const u32* __restrict__ totals,
    u32* __restrict__ mm, u32* __restrict__ wstart,
    u32* __restrict__ pal_u32)
{
    __shared__ u32 sc[NBKT];
    const int tid = threadIdx.x;

    for (int t = tid; t < FID * 4; t += 512)
        pal_u32[t] = __float2uint_rn(__fmul_rn(palette[t], FPSCALE));

    const u32 t0 = totals[tid];
    sc[tid] = t0; __syncthreads();
    #pragma unroll
    for (int o = 1; o < NBKT; o <<= 1) {
        u32 v = (tid >= o) ? sc[tid - o] : 0u;
        __syncthreads(); sc[tid] += v; __syncthreads();
    }
    const u32 total = sc[NBKT - 1];

    const u32 m = 1u + (total ? (u32)((504ull * t0) / total) : 0u);
    mm[tid] = m;
    __syncthreads(); sc[tid] = m; __syncthreads();
    #pragma unroll
    for (int o = 1; o < NBKT; o <<= 1) {
        u32 v = (tid >= o) ? sc[tid - o] : 0u;
        __syncthreads(); sc[tid] += v; __syncthreads();
    }
    wstart[tid] = sc[tid] - m;
    if (tid == NBKT - 1) wstart[NBKT] = sc[NBKT - 1];
}

// ---------------------------------------------------------------------------
// K4 v9: CHANNEL-SPLIT v6. Round-16's flat-balanced walk (per-record search
// + one-ahead prefetch, the 86us champion) but each block accumulates only
// TWO channels into ONE 16 KB u64 tile -> LDS 22.2 KB -> 7 blocks/CU
// (~56 waves/CU, 2x TLP vs v6-v8's 4 blocks). grid = 2*PARTCH; half =
// blockIdx/PARTCH selects ch01 or ch23. Records read twice (L3-resident;
// rounds 15/16 proved time is traffic-insensitive).
// ---------------------------------------------------------------------------
__global__ __launch_bounds__(512) void k_accum(
    const u32* __restrict__ pal_u32,
    const u32* __restrict__ counts_t, const u32* __restrict__ lpre_t,
    const u32* __restrict__ mm, const u32* __restrict__ wstart,
    const u32* __restrict__ blockmajor,
    u32* __restrict__ partA, u32* __restrict__ partB)
{
    __shared__ u64 tileH[BKTPX];        // 2 channels (16 KB)
    __shared__ u32 s_ml[MSTG];          // staged lp (2 KB)
    __shared__ u32 s_pfx[MSTG + 1];
    __shared__ u32 s_ws[NBKT + 1];
    const int tid = threadIdx.x;
    const int half = (blockIdx.x >= PARTCH) ? 1 : 0;
    const int w = blockIdx.x - half * PARTCH;
    if (w >= PARTCH) return;

    if (tid < NBKT) s_ws[tid] = wstart[tid];
    if (tid == 0)   s_ws[NBKT] = wstart[NBKT];
    __syncthreads();
    if ((u32)w >= s_ws[NBKT]) return;   // uniform per block

    int b = 0;
    #pragma unroll
    for (int step = 256; step; step >>= 1)
        if (b + step <= NBKT - 1 && s_ws[b + step] <= (u32)w) b += step;

    for (int t = tid; t < BKTPX; t += 512) tileH[t] = 0ull;

    const u32 m = mm[b], cch = (u32)w - s_ws[b];
    const u32 gs = (u32)(((u64)NB * cch) / m);
    const u32 ge = (u32)(((u64)NB * (cch + 1)) / m);

    const u32* palh = pal_u32 + half * 2;   // ch01 or ch23 pairs
    const u32* ct = counts_t + (size_t)b * NB;
    const u32* lt = lpre_t + (size_t)b * NB;

    for (u32 g0 = gs; g0 < ge; g0 += MSTG) {
        const u32 nm = min((u32)MSTG, ge - g0);
        __syncthreads();                 // protect prior stage's readers
        const u32 myc = (tid < (int)nm) ? ct[g0 + tid] : 0u;   // coalesced
        if (tid < (int)nm) s_ml[tid] = lt[g0 + tid];           // coalesced
        s_pfx[tid + 1] = myc;
        if (tid == 0) s_pfx[0] = 0u;
        __syncthreads();
        // Hillis-Steele inclusive scan over s_pfx[1..512].
        #pragma unroll
        for (int o = 1; o < MSTG; o <<= 1) {
            const u32 v = (tid >= o) ? s_pfx[tid - o + 1] : 0u;
            __syncthreads();
            s_pfx[tid + 1] += v;
            __syncthreads();
        }
        const u32 R = s_pfx[MSTG];       // records in this stage

        // Flat, balanced walk with one-ahead pipeline (v6 structure).
        u32 idx = (u32)tid;
        u32 r_c = 0;
        if (idx < R) {
            u32 g = 0;
            #pragma unroll
            for (int step = 256; step; step >>= 1)
                if (s_pfx[g + step] <= idx) g += step;
            r_c = blockmajor[(size_t)(g0 + g) * SEGW + s_ml[g] +
                             (idx - s_pfx[g])];
        }
        while (idx < R) {
            const u32 nidx = idx + 512;
            u32 r_n = 0;
            if (nidx < R) {
                u32 g = 0;
                #pragma unroll
                for (int step = 256; step; step >>= 1)
                    if (s_pfx[g + step] <= nidx) g += step;
                r_n = blockmajor[(size_t)(g0 + g) * SEGW + s_ml[g] +
                                 (nidx - s_pfx[g])];   // prefetch next
            }
            const u32 pb = (r_c & 1023u) * 4;
            const u32 c0v = palh[pb], c1v = palh[pb + 1];
            const u32 local = (r_c >> 10) & (BKTPX - 1);
            atomicAdd(&tileH[local], (u64)c0v | ((u64)c1v << 32));
            idx = nidx; r_c = r_n;
        }
    }
    __syncthreads();

    u32* dst = htile_ptr(partA, partB, (u32)(half * PARTCH + w));
    const uint2* src = (const uint2*)tileH;
    for (int t = tid; t < BKTPX; t += 512)
        ((uint2*)dst)[t] = src[t];
}

// ---------------------------------------------------------------------------
// K5: sum partial half-tiles per bucket, unpack, add raw_image, write out.
// ---------------------------------------------------------------------------
__global__ __launch_bounds__(256) void k_final(
    const u32* __restrict__ partA, const u32* __restrict__ partB,
    const u32* __restrict__ wstart,
    const float* __restrict__ raw, float* __restrict__ out)
{
    const int p = blockIdx.x * 256 + threadIdx.x;
    const int b = p >> 11, local = p & (BKTPX - 1);
    u32 a0 = 0, a1 = 0, a2 = 0, a3 = 0;
    const u32 w0 = wstart[b], w1 = wstart[b + 1];
    for (u32 w = w0; w < w1; ++w) {
        const uint2 vA = ((const uint2*)htile_ptr_c(partA, partB, w))[local];
        const uint2 vB = ((const uint2*)htile_ptr_c(partA, partB,
                                                    PARTCH + w))[local];
        a0 += vA.x; a1 += vA.y; a2 += vB.x; a3 += vB.y;
    }
    out[0*(size_t)HW + p] = __fadd_rn(raw[0*(size_t)HW + p], __fmul_rn((float)a0, FPINV));
    out[1*(size_t)HW + p] = __fadd_rn(raw[1*(size_t)HW + p], __fmul_rn((float)a1, FPINV));
    out[2*(size_t)HW + p] = __fadd_rn(raw[2*(size_t)HW + p], __fmul_rn((float)a2, FPINV));
    out[3*(size_t)HW + p] = __fadd_rn(raw[3*(size_t)HW + p], __fmul_rn((float)a3, FPINV));
}

// ---------------------------------------------------------------------------
// Fallback (ws too small): packed u64 global atomics (round-3 path).
// ---------------------------------------------------------------------------
__global__ __launch_bounds__(256) void flame_accum_packed(
    const float* __restrict__ palette,
    const float* __restrict__ Amat, const float* __restrict__ bvec,
    const float* __restrict__ fcolor,
    const float* __restrict__ xy0, const float* __restrict__ c0,
    const float* __restrict__ minv, const float* __restrict__ rangev,
    const int* __restrict__ fn_idx, const int* __restrict__ skipk_ptr,
    u64* __restrict__ ws)
{
    __shared__ __align__(16) float s_pal[FID * 4];
    __shared__ float s_tab[NF * 8];
    for (int t = threadIdx.x; t < FID; t += 256)
        ((float4*)s_pal)[t] = ((const float4*)palette)[t];
    LOAD_TABLES();
    __syncthreads();

    const int i = blockIdx.x * 256 + threadIdx.x;
    if (i >= NPTS) return;
    const int   skipk = skipk_ptr[0];
    const float minx = minv[0], miny = minv[1];
    const float rx = rangev[0], ry = rangev[1];
    const float2 xyv = ((const float2*)xy0)[i];
    float x = xyv.x, y = xyv.y, c = c0[i];
    for (int k = 0; k < KSTEPS; ++k) {
        const int idx = fn_idx[(size_t)k * NPTS + i];
        int xb, yb; bool inb;
        FLAME_STEP(idx, k);
        if (inb) {
            int pi = (int)__fadd_rn(__fmul_rn(c, 999.0f), 0.0005f);
            pi = min(max(pi, 0), FID - 1);
            const float4 col = *(const float4*)&s_pal[pi * 4];
            const u32 u0 = __float2uint_rn(__fmul_rn(col.x, FPSCALE));
            const u32 u1 = __float2uint_rn(__fmul_rn(col.y, FPSCALE));
            const u32 u2 = __float2uint_rn(__fmul_rn(col.z, FPSCALE));
            const u32 u3 = __float2uint_rn(__fmul_rn(col.w, FPSCALE));
            u64* p = ws + ((size_t)xb * IMG_W + yb) * 2;
            atomicAdd(p + 0, (u64)u0 | ((u64)u1 << 32));
            atomicAdd(p + 1, (u64)u2 | ((u64)u3 << 32));
        }
    }
}

__global__ __launch_bounds__(256) void reduce_packed(
    const u64* __restrict__ ws, const float* __restrict__ raw_image,
    float* __restrict__ out)
{
    const int p = blockIdx.x * 256 + threadIdx.x;
    if (p >= HW) return;
    const u64 w0 = ws[(size_t)p * 2 + 0];
    const u64 w1 = ws[(size_t)p * 2 + 1];
    out[0*(size_t)HW+p] = raw_image[0*(size_t)HW+p] + (float)(u32)(w0 & 0xffffffffull) * FPINV;
    out[1*(size_t)HW+p] = raw_image[1*(size_t)HW+p] + (float)(u32)(w0 >> 32)           * FPINV;
    out[2*(size_t)HW+p] = raw_image[2*(size_t)HW+p] + (float)(u32)(w1 & 0xffffffffull) * FPINV;
    out[3*(size_t)HW+p] = raw_image[3*(size_t)HW+p] + (float)(u32)(w1 >> 32)           * FPINV;
}

extern "C" void kernel_launch(void* const* d_in, const int* in_sizes, int n_in,
                              void* d_out, int out_size, void* d_ws, size_t ws_size,
                              hipStream_t stream) {
    const float* raw_image = (const float*)d_in[0];
    const float* palette   = (const float*)d_in[1];
    const float* A         = (const float*)d_in[2];
    const float* b         = (const float*)d_in[3];
    const float* fcolor    = (const float*)d_in[4];
    const float* xy0       = (const float*)d_in[5];
    const float* c0        = (const float*)d_in[6];
    const float* minv      = (const float*)d_in[7];
    const float* rangev    = (const float*)d_in[8];
    const int*   fn_idx    = (const int*)d_in[9];
    const int*   skipk     = (const int*)d_in[10];
    float* img = (float*)d_out;

    // ws layout (u32 units). counts+lpre (16 MB) are dead after k_transpose,
    // so the first PARTA_T half-tiles alias them (partA); remaining half-
    // tiles live in partB after blockmajor.
    u32* ws = (u32*)d_ws;
    const size_t NBG = (size_t)NB * NBKT;                  // 2,000,384
    u32* counts     = ws;                                  // NBG
    u32* lpre       = counts + NBG;                        // NBG
    u32* counts_t   = lpre + NBG;                          // NBG
    u32* lpre_t     = counts_t + NBG;                      // NBG
    u32* totals     = lpre_t + NBG;                        // 512
    u32* mm         = totals + NBKT;                       // 512
    u32* wstart     = mm + NBKT;                           // 513 (pad 1024)
    u32* pal_u32    = wstart + 1024;                       // 4096
    u32* blockmajor = pal_u32 + 4096;                      // NB*SEGW (128MB)
    u32* partB      = blockmajor + (size_t)NB * SEGW;      // (HTILES-976)*HTW
    u32* partA      = counts;                              // aliased
    const size_t need_u32 = (size_t)(partB - ws) +
                            (size_t)(HTILES - PARTA_T) * HTW;
    const size_t NEED = need_u32 * sizeof(u32);            // ~177.4 MB

    if (ws_size >= NEED) {
        k_flame<<<dim3(NB), 256, 0, stream>>>(A, b, fcolor, xy0, c0, minv,
                                              rangev, fn_idx, skipk,
                                              counts, lpre, blockmajor);
        k_transpose<<<dim3(NBKT), 256, 0, stream>>>(counts, lpre,
                                                    counts_t, lpre_t, totals);
        k_meta<<<dim3(1), 512, 0, stream>>>(palette, totals, mm, wstart,
                                            pal_u32);
        k_accum<<<dim3(K5G2), 512, 0, stream>>>(pal_u32, counts_t, lpre_t, mm,
                                                wstart, blockmajor,
                                                partA, partB);
        k_final<<<dim3(HW / 256), 256, 0, stream>>>(partA, partB, wstart,
                                                    raw_image, img);
    } else {
        const size_t need2 = (size_t)HW * 2 * sizeof(u64);
        hipMemsetAsync(d_ws, 0, need2, stream);
        flame_accum_packed<<<dim3(NB), 256, 0, stream>>>(
            palette, A, b, fcolor, xy0, c0, minv, rangev, fn_idx, skipk,
            (u64*)d_ws);
        reduce_packed<<<dim3((HW + 255) / 256), 256, 0, stream>>>(
            (const u64*)d_ws, raw_image, img);
    }
}

// Round 20
// 178.041 us; speedup vs baseline: 1.3117x; 1.3117x over previous
//
#include <hip/hip_runtime.h>

typedef unsigned int u32;
typedef unsigned long long u64;

#define NPTS   1000000
#define KSTEPS 32
#define NF     8
#define IMG_H  1024
#define IMG_W  1024
#define FID    1000
#define HW     (IMG_H * IMG_W)
#define NB     3907            // ceil(NPTS/256)
#define NBKT   512             // bucket = pixel >> 11  (2 image rows)
#define BKTPX  2048            // pixels per bucket
#define SEGW   (256 * KSTEPS)  // 8192 words per block-major segment
#define K5G    1024            // accumulate grid (>= PARTCH)
#define PARTCH 1016            // max chunks = 512 + 504
#define PARTA_CH 488           // chunk tiles aliased over counts+lpre region
#define MSTG   512             // meta staging span (g's per stage)
#define FPSCALE 4194304.0f     // 2^22 fixed point; capacity 1024 > max sum 488
#define FPINV   (1.0f / 4194304.0f)

// Extract step K's function index from packed nibble words p0..p3.
#define GETIDX(K)                                                              \
    ((int)(((((K) >> 3) == 0 ? p0 : ((K) >> 3) == 1 ? p1                       \
            : ((K) >> 3) == 2 ? p2 : p3) >> (((K) & 7) * 4)) & 7u))

// One chaos-game step, numpy-exact (no FMA contraction). Scalar LDS table
// reads: 8 distinct rows max -> broadcast/2-way aliasing (free on CDNA4).
#define FLAME_STEP(IDX, K)                                                     \
  {                                                                            \
    const float a00 = s_tab[(IDX)*8+0], a01 = s_tab[(IDX)*8+1];                \
    const float a10 = s_tab[(IDX)*8+2], a11 = s_tab[(IDX)*8+3];                \
    const float b0  = s_tab[(IDX)*8+4], b1  = s_tab[(IDX)*8+5];                \
    const float fc  = s_tab[(IDX)*8+6];                                        \
    const float nx = __fadd_rn(__fadd_rn(__fmul_rn(a00,x),__fmul_rn(a01,y)),b0);\
    const float ny = __fadd_rn(__fadd_rn(__fmul_rn(a10,x),__fmul_rn(a11,y)),b1);\
    x = nx; y = ny;                                                            \
    c = __fmul_rn(__fadd_rn(c, fc), 0.5f);                                     \
    xb = (int)__fmul_rn(__fsub_rn(x, minx), rx);                               \
    yb = (int)__fmul_rn(__fsub_rn(y, miny), ry);                               \
    inb = (xb >= 0) & (xb < IMG_W) & (yb >= 0) & (yb < IMG_H) & ((K) >= skipk);\
  }

#define LOAD_TABLES()                                                          \
    if (threadIdx.x < NF) {                                                    \
        const int f = threadIdx.x;                                             \
        s_tab[f*8+0] = Amat[f*4+0]; s_tab[f*8+1] = Amat[f*4+1];                \
        s_tab[f*8+2] = Amat[f*4+2]; s_tab[f*8+3] = Amat[f*4+3];                \
        s_tab[f*8+4] = bvec[f*2+0]; s_tab[f*8+5] = bvec[f*2+1];                \
        s_tab[f*8+6] = fcolor[f];   s_tab[f*8+7] = 0.0f;                       \
    }

__device__ __forceinline__ u32* part_ptr(u32* partA, u32* partB, u32 w) {
    return (w < PARTA_CH) ? partA + (size_t)w * (BKTPX * 4)
                          : partB + (size_t)(w - PARTA_CH) * (BKTPX * 4);
}
__device__ __forceinline__ const u32* part_ptr_c(const u32* partA,
                                                 const u32* partB, u32 w) {
    return (w < PARTA_CH) ? partA + (size_t)w * (BKTPX * 4)
                          : partB + (size_t)(w - PARTA_CH) * (BKTPX * 4);
}

// Wave-level inclusive scan of v across the 64-lane wave (6 shfl steps).
__device__ __forceinline__ u32 wave_incl_scan(u32 v, int lane) {
    #pragma unroll
    for (int o = 1; o < 64; o <<= 1) {
        const u32 n = __shfl_up(v, o);
        if (lane >= o) v += n;
    }
    return v;
}

// ---------------------------------------------------------------------------
// K1: the ONLY flame pass. Scan now shuffle-based: 2 barriers, not 18.
// ---------------------------------------------------------------------------
__global__ __launch_bounds__(256) void k_flame(
    const float* __restrict__ Amat, const float* __restrict__ bvec,
    const float* __restrict__ fcolor,
    const float* __restrict__ xy0, const float* __restrict__ c0,
    const float* __restrict__ minv, const float* __restrict__ rangev,
    const int* __restrict__ fn_idx, const int* __restrict__ skipk_ptr,
    u32* __restrict__ counts, u32* __restrict__ lpre,
    u32* __restrict__ blockmajor)
{
    __shared__ u32 s_rec[SEGW];          // 32 KB
    __shared__ u32 s_cnt[NBKT];          // counts, then cursors
    __shared__ u32 s_wsum[4];
    __shared__ u32 s_vt;
    __shared__ float s_tab[NF * 8];
    const int tid = threadIdx.x;
    const int lane = tid & 63, wav = tid >> 6;

    s_cnt[tid] = 0u; s_cnt[tid + 256] = 0u;
    LOAD_TABLES();
    __syncthreads();

    const int i = blockIdx.x * 256 + tid;
    u32 rec[KSTEPS];

    if (i < NPTS) {
        u32 p0 = 0, p1 = 0, p2 = 0, p3 = 0;
        #pragma unroll
        for (int k = 0; k < 8; ++k)
            p0 |= ((u32)fn_idx[(size_t)k * NPTS + i] & 7u) << (k * 4);
        #pragma unroll
        for (int k = 0; k < 8; ++k)
            p1 |= ((u32)fn_idx[(size_t)(k + 8) * NPTS + i] & 7u) << (k * 4);
        #pragma unroll
        for (int k = 0; k < 8; ++k)
            p2 |= ((u32)fn_idx[(size_t)(k + 16) * NPTS + i] & 7u) << (k * 4);
        #pragma unroll
        for (int k = 0; k < 8; ++k)
            p3 |= ((u32)fn_idx[(size_t)(k + 24) * NPTS + i] & 7u) << (k * 4);

        const int   skipk = skipk_ptr[0];
        const float minx = minv[0], miny = minv[1];
        const float rx = rangev[0], ry = rangev[1];
        const float2 xyv = ((const float2*)xy0)[i];
        float x = xyv.x, y = xyv.y, c = c0[i];
        #pragma unroll
        for (int k = 0; k < KSTEPS; ++k) {
            const int idx = GETIDX(k);
            int xb, yb; bool inb;
            FLAME_STEP(idx, k);
            u32 r = 0xFFFFFFFFu;
            if (inb) {
                int pi = (int)__fadd_rn(__fmul_rn(c, 999.0f), 0.0005f);
                pi = min(max(pi, 0), FID - 1);
                r = (((u32)(xb << 10 | yb)) << 10) | (u32)pi;
                atomicAdd(&s_cnt[r >> 21], 1u);
            }
            rec[k] = r;
        }
    }
    __syncthreads();

    // Shuffle-based exclusive scan over 512 bucket counts (2 per thread).
    const u32 cA = s_cnt[2 * tid], cB = s_cnt[2 * tid + 1];
    const u32 psum = cA + cB;
    u32 v = wave_incl_scan(psum, lane);
    if (lane == 63) s_wsum[wav] = v;
    __syncthreads();
    u32 off = 0;
    #pragma unroll
    for (int wv = 0; wv < 4; ++wv)
        if (wv < wav) off += s_wsum[wv];
    const u32 incl = v + off;
    const u32 excl = incl - psum;

    // Cursors in LDS; per-(block,bucket) meta to global (coalesced).
    s_cnt[2 * tid] = excl; s_cnt[2 * tid + 1] = excl + cA;
    const size_t g0 = (size_t)blockIdx.x * NBKT;
    lpre[g0 + 2 * tid] = excl;  lpre[g0 + 2 * tid + 1] = excl + cA;
    counts[g0 + 2 * tid] = cA;  counts[g0 + 2 * tid + 1] = cB;
    if (tid == 255) s_vt = incl;         // total valid records
    __syncthreads();

    // Re-scatter rec[] from VGPRs into LDS, bucket-sorted.
    if (i < NPTS) {
        #pragma unroll
        for (int k = 0; k < KSTEPS; ++k) {
            const u32 r = rec[k];
            if (r != 0xFFFFFFFFu) {
                const u32 pos = atomicAdd(&s_cnt[r >> 21], 1u);
                s_rec[pos] = r;
            }
        }
    }
    __syncthreads();

    // Dense copy to block-major segment (uint4).
    const u32 vt = s_vt;
    u32* dst = blockmajor + (size_t)blockIdx.x * SEGW;
    const u32 nv4 = vt >> 2;
    for (u32 q = tid; q < nv4; q += 256)
        ((uint4*)dst)[q] = make_uint4(s_rec[4*q], s_rec[4*q+1],
                                      s_rec[4*q+2], s_rec[4*q+3]);
    for (u32 j = (nv4 << 2) + tid; j < vt; j += 256) dst[j] = s_rec[j];
}

// ---------------------------------------------------------------------------
// K2: transpose meta to bucket-major + per-bucket totals. grid = NBKT.
// ---------------------------------------------------------------------------
__global__ __launch_bounds__(256) void k_transpose(
    const u32* __restrict__ counts, const u32* __restrict__ lpre,
    u32* __restrict__ counts_t, u32* __restrict__ lpre_t,
    u32* __restrict__ totals)
{
    const int b = blockIdx.x, tid = threadIdx.x;
    u32 s = 0;
    for (int row = tid; row < NB; row += 256) {
        const u32 cv = counts[(size_t)row * NBKT + b];
        const u32 lv = lpre[(size_t)row * NBKT + b];
        counts_t[(size_t)b * NB + row] = cv;
        lpre_t[(size_t)b * NB + row] = lv;
        s += cv;
    }
    __shared__ u32 red[256];
    red[tid] = s; __syncthreads();
    #pragma unroll
    for (int o = 128; o; o >>= 1) {
        if (tid < o) red[tid] += red[tid + o];
        __syncthreads();
    }
    if (tid == 0) totals[b] = red[0];
}

// ---------------------------------------------------------------------------
// K3: chunk counts m[b], wstart scan, fixed-point palette. 1 wg x 512.
// ---------------------------------------------------------------------------
__global__ __launch_bounds__(512) void k_meta(
    const float* __restrict__ palette,
    const u32* __restrict__ totals,
    u32* __restrict__ mm, u32* __restrict__ wstart,
    u32* __restrict__ pal_u32)
{
    __shared__ u32 sc[NBKT];
    const int tid = threadIdx.x;

    for (int t = tid; t < FID * 4; t += 512)
        pal_u32[t] = __float2uint_rn(__fmul_rn(palette[t], FPSCALE));

    const u32 t0 = totals[tid];
    sc[tid] = t0; __syncthreads();
    #pragma unroll
    for (int o = 1; o < NBKT; o <<= 1) {
        u32 v = (tid >= o) ? sc[tid - o] : 0u;
        __syncthreads(); sc[tid] += v; __syncthreads();
    }
    const u32 total = sc[NBKT - 1];

    const u32 m = 1u + (total ? (u32)((504ull * t0) / total) : 0u);
    mm[tid] = m;
    __syncthreads(); sc[tid] = m; __syncthreads();
    #pragma unroll
    for (int o = 1; o < NBKT; o <<= 1) {
        u32 v = (tid >= o) ? sc[tid - o] : 0u;
        __syncthreads(); sc[tid] += v; __syncthreads();
    }
    wstart[tid] = sc[tid] - m;
    if (tid == NBKT - 1) wstart[NBKT] = sc[NBKT - 1];
}

// ---------------------------------------------------------------------------
// K4 v10: round-16 v6 walk (per-record search + one-ahead prefetch, the
// 86us champion) with the per-stage Hillis-Steele scan (18 barriers)
// replaced by a shuffle scan (2 barriers). Nothing else changed.
// LDS = 38.4 KB -> 4 blocks/CU.
// ---------------------------------------------------------------------------
__global__ __launch_bounds__(512) void k_accum(
    const u32* __restrict__ pal_u32,
    const u32* __restrict__ counts_t, const u32* __restrict__ lpre_t,
    const u32* __restrict__ mm, const u32* __restrict__ wstart,
    const u32* __restrict__ blockmajor,
    u32* __restrict__ partA, u32* __restrict__ partB)
{
    __shared__ u64 tileA[BKTPX];        // ch0|ch1 (16 KB)
    __shared__ u64 tileB[BKTPX];        // ch2|ch3 (16 KB)
    __shared__ u32 s_ml[MSTG];          // staged lp (2 KB)
    __shared__ u32 s_pfx[MSTG + 1];     // run starts
    __shared__ u32 s_ws[NBKT + 1];
    __shared__ u32 s_wsum[8];
    const int tid = threadIdx.x, w = blockIdx.x;
    const int lane = tid & 63, wav = tid >> 6;

    if (tid < NBKT) s_ws[tid] = wstart[tid];
    if (tid == 0)   s_ws[NBKT] = wstart[NBKT];
    __syncthreads();
    if ((u32)w >= s_ws[NBKT]) return;   // uniform per block

    int b = 0;
    #pragma unroll
    for (int step = 256; step; step >>= 1)
        if (b + step <= NBKT - 1 && s_ws[b + step] <= (u32)w) b += step;

    for (int t = tid; t < BKTPX; t += 512) { tileA[t] = 0ull; tileB[t] = 0ull; }

    const u32 m = mm[b], cch = (u32)w - s_ws[b];
    const u32 gs = (u32)(((u64)NB * cch) / m);
    const u32 ge = (u32)(((u64)NB * (cch + 1)) / m);

    const uint4* pal4 = (const uint4*)pal_u32;
    const u32* ct = counts_t + (size_t)b * NB;
    const u32* lt = lpre_t + (size_t)b * NB;

    for (u32 g0 = gs; g0 < ge; g0 += MSTG) {
        const u32 nm = min((u32)MSTG, ge - g0);
        __syncthreads();                 // protect prior stage's readers
        const u32 myc = (tid < (int)nm) ? ct[g0 + tid] : 0u;   // coalesced
        if (tid < (int)nm) s_ml[tid] = lt[g0 + tid];           // coalesced

        // Shuffle-based inclusive scan of myc over 512 threads (2 barriers).
        u32 v = wave_incl_scan(myc, lane);
        if (lane == 63) s_wsum[wav] = v;
        __syncthreads();
        u32 off = 0;
        #pragma unroll
        for (int wv = 0; wv < 8; ++wv)
            if (wv < wav) off += s_wsum[wv];
        s_pfx[tid + 1] = v + off;        // inclusive
        if (tid == 0) s_pfx[0] = 0u;
        __syncthreads();
        const u32 R = s_pfx[MSTG];       // records in this stage

        // Flat, balanced walk with one-ahead pipeline (v6 structure).
        u32 idx = (u32)tid;
        u32 r_c = 0;
        if (idx < R) {
            u32 g = 0;
            #pragma unroll
            for (int step = 256; step; step >>= 1)
                if (s_pfx[g + step] <= idx) g += step;
            r_c = blockmajor[(size_t)(g0 + g) * SEGW + s_ml[g] +
                             (idx - s_pfx[g])];
        }
        while (idx < R) {
            const u32 nidx = idx + 512;
            u32 r_n = 0;
            if (nidx < R) {
                u32 g = 0;
                #pragma unroll
                for (int step = 256; step; step >>= 1)
                    if (s_pfx[g + step] <= nidx) g += step;
                r_n = blockmajor[(size_t)(g0 + g) * SEGW + s_ml[g] +
                                 (nidx - s_pfx[g])];   // prefetch next
            }
            const uint4 pc = pal4[r_c & 1023u];        // one palette load
            const u32 local = (r_c >> 10) & (BKTPX - 1);
            atomicAdd(&tileA[local], (u64)pc.x | ((u64)pc.y << 32));
            atomicAdd(&tileB[local], (u64)pc.z | ((u64)pc.w << 32));
            idx = nidx; r_c = r_n;
        }
    }
    __syncthreads();

    uint4* dst = (uint4*)part_ptr(partA, partB, (u32)w);
    for (int t = tid; t < BKTPX; t += 512)
        dst[t] = make_uint4((u32)tileA[t], (u32)(tileA[t] >> 32),
                            (u32)tileB[t], (u32)(tileB[t] >> 32));
}

// ---------------------------------------------------------------------------
// K5: sum partial tiles per bucket, unpack, add raw_image, write CHW out.
// ---------------------------------------------------------------------------
__global__ __launch_bounds__(256) void k_final(
    const u32* __restrict__ partA, const u32* __restrict__ partB,
    const u32* __restrict__ wstart,
    const float* __restrict__ raw, float* __restrict__ out)
{
    const int p = blockIdx.x * 256 + threadIdx.x;
    const int b = p >> 11, local = p & (BKTPX - 1);
    u32 a0 = 0, a1 = 0, a2 = 0, a3 = 0;
    const u32 w0 = wstart[b], w1 = wstart[b + 1];
    for (u32 w = w0; w < w1; ++w) {
        const uint4 v = ((const uint4*)part_ptr_c(partA, partB, w))[local];
        a0 += v.x; a1 += v.y; a2 += v.z; a3 += v.w;
    }
    out[0*(size_t)HW + p] = __fadd_rn(raw[0*(size_t)HW + p], __fmul_rn((float)a0, FPINV));
    out[1*(size_t)HW + p] = __fadd_rn(raw[1*(size_t)HW + p], __fmul_rn((float)a1, FPINV));
    out[2*(size_t)HW + p] = __fadd_rn(raw[2*(size_t)HW + p], __fmul_rn((float)a2, FPINV));
    out[3*(size_t)HW + p] = __fadd_rn(raw[3*(size_t)HW + p], __fmul_rn((float)a3, FPINV));
}

// ---------------------------------------------------------------------------
// Fallback (ws too small): packed u64 global atomics (round-3 path).
// ---------------------------------------------------------------------------
__global__ __launch_bounds__(256) void flame_accum_packed(
    const float* __restrict__ palette,
    const float* __restrict__ Amat, const float* __restrict__ bvec,
    const float* __restrict__ fcolor,
    const float* __restrict__ xy0, const float* __restrict__ c0,
    const float* __restrict__ minv, const float* __restrict__ rangev,
    const int* __restrict__ fn_idx, const int* __restrict__ skipk_ptr,
    u64* __restrict__ ws)
{
    __shared__ __align__(16) float s_pal[FID * 4];
    __shared__ float s_tab[NF * 8];
    for (int t = threadIdx.x; t < FID; t += 256)
        ((float4*)s_pal)[t] = ((const float4*)palette)[t];
    LOAD_TABLES();
    __syncthreads();

    const int i = blockIdx.x * 256 + threadIdx.x;
    if (i >= NPTS) return;
    const int   skipk = skipk_ptr[0];
    const float minx = minv[0], miny = minv[1];
    const float rx = rangev[0], ry = rangev[1];
    const float2 xyv = ((const float2*)xy0)[i];
    float x = xyv.x, y = xyv.y, c = c0[i];
    for (int k = 0; k < KSTEPS; ++k) {
        const int idx = fn_idx[(size_t)k * NPTS + i];
        int xb, yb; bool inb;
        FLAME_STEP(idx, k);
        if (inb) {
            int pi = (int)__fadd_rn(__fmul_rn(c, 999.0f), 0.0005f);
            pi = min(max(pi, 0), FID - 1);
            const float4 col = *(const float4*)&s_pal[pi * 4];
            const u32 u0 = __float2uint_rn(__fmul_rn(col.x, FPSCALE));
            const u32 u1 = __float2uint_rn(__fmul_rn(col.y, FPSCALE));
            const u32 u2 = __float2uint_rn(__fmul_rn(col.z, FPSCALE));
            const u32 u3 = __float2uint_rn(__fmul_rn(col.w, FPSCALE));
            u64* p = ws + ((size_t)xb * IMG_W + yb) * 2;
            atomicAdd(p + 0, (u64)u0 | ((u64)u1 << 32));
            atomicAdd(p + 1, (u64)u2 | ((u64)u3 << 32));
        }
    }
}

__global__ __launch_bounds__(256) void reduce_packed(
    const u64* __restrict__ ws, const float* __restrict__ raw_image,
    float* __restrict__ out)
{
    const int p = blockIdx.x * 256 + threadIdx.x;
    if (p >= HW) return;
    const u64 w0 = ws[(size_t)p * 2 + 0];
    const u64 w1 = ws[(size_t)p * 2 + 1];
    out[0*(size_t)HW+p] = raw_image[0*(size_t)HW+p] + (float)(u32)(w0 & 0xffffffffull) * FPINV;
    out[1*(size_t)HW+p] = raw_image[1*(size_t)HW+p] + (float)(u32)(w0 >> 32)           * FPINV;
    out[2*(size_t)HW+p] = raw_image[2*(size_t)HW+p] + (float)(u32)(w1 & 0xffffffffull) * FPINV;
    out[3*(size_t)HW+p] = raw_image[3*(size_t)HW+p] + (float)(u32)(w1 >> 32)           * FPINV;
}

extern "C" void kernel_launch(void* const* d_in, const int* in_sizes, int n_in,
                              void* d_out, int out_size, void* d_ws, size_t ws_size,
                              hipStream_t stream) {
    const float* raw_image = (const float*)d_in[0];
    const float* palette   = (const float*)d_in[1];
    const float* A         = (const float*)d_in[2];
    const float* b         = (const float*)d_in[3];
    const float* fcolor    = (const float*)d_in[4];
    const float* xy0       = (const float*)d_in[5];
    const float* c0        = (const float*)d_in[6];
    const float* minv      = (const float*)d_in[7];
    const float* rangev    = (const float*)d_in[8];
    const int*   fn_idx    = (const int*)d_in[9];
    const int*   skipk     = (const int*)d_in[10];
    float* img = (float*)d_out;

    // ws layout (u32 units). counts+lpre (16 MB) are dead after k_transpose,
    // so the first PARTA_CH partial tiles alias them (partA); the remaining
    // tiles live in partB after blockmajor.
    u32* ws = (u32*)d_ws;
    const size_t NBG = (size_t)NB * NBKT;                  // 2,000,384
    u32* counts     = ws;                                  // NBG
    u32* lpre       = counts + NBG;                        // NBG
    u32* counts_t   = lpre + NBG;                          // NBG
    u32* lpre_t     = counts_t + NBG;                      // NBG
    u32* totals     = lpre_t + NBG;                        // 512
    u32* mm         = totals + NBKT;                       // 512
    u32* wstart     = mm + NBKT;                           // 513 (pad 1024)
    u32* pal_u32    = wstart + 1024;                       // 4096
    u32* blockmajor = pal_u32 + 4096;                      // NB*SEGW (128MB)
    u32* partB      = blockmajor + (size_t)NB * SEGW;      // (PARTCH-488)*8192
    u32* partA      = counts;                              // aliased
    const size_t need_u32 = (size_t)(partB - ws) +
                            (size_t)(PARTCH - PARTA_CH) * (BKTPX * 4);
    const size_t NEED = need_u32 * sizeof(u32);            // ~177.36 MB

    if (ws_size >= NEED) {
        k_flame<<<dim3(NB), 256, 0, stream>>>(A, b, fcolor, xy0, c0, minv,
                                              rangev, fn_idx, skipk,
                                              counts, lpre, blockmajor);
        k_transpose<<<dim3(NBKT), 256, 0, stream>>>(counts, lpre,
                                                    counts_t, lpre_t, totals);
        k_meta<<<dim3(1), 512, 0, stream>>>(palette, totals, mm, wstart,
                                            pal_u32);
        k_accum<<<dim3(K5G), 512, 0, stream>>>(pal_u32, counts_t, lpre_t, mm,
                                               wstart, blockmajor,
                                               partA, partB);
        k_final<<<dim3(HW / 256), 256, 0, stream>>>(partA, partB, wstart,
                                                    raw_image, img);
    } else {
        const size_t need2 = (size_t)HW * 2 * sizeof(u64);
        hipMemsetAsync(d_ws, 0, need2, stream);
        flame_accum_packed<<<dim3(NB), 256, 0, stream>>>(
            palette, A, b, fcolor, xy0, c0, minv, rangev, fn_idx, skipk,
            (u64*)d_ws);
        reduce_packed<<<dim3((HW + 255) / 256), 256, 0, stream>>>(
            (const u64*)d_ws, raw_image, img);
    }
}

// Round 21
// 162.799 us; speedup vs baseline: 1.4345x; 1.0936x over previous
//
#include <hip/hip_runtime.h>

typedef unsigned int u32;
typedef unsigned long long u64;

#define NPTS   1000000
#define KSTEPS 32
#define NF     8
#define IMG_H  1024
#define IMG_W  1024
#define FID    1000
#define HW     (IMG_H * IMG_W)
#define NB     3907            // ceil(NPTS/256)
#define NBKT   512             // bucket = pixel >> 11  (2 image rows)
#define BKTPX  2048            // pixels per bucket
#define SEGW   (256 * KSTEPS)  // 8192 words per block-major segment
#define K5G    1024            // accumulate grid (>= PARTCH)
#define PARTCH 1016            // max chunks = 512 + 504
#define PARTA_CH 488           // chunk tiles aliased over counts+lpre region
#define MSTG   512             // meta staging span (g's per stage)
#define TT     64              // transpose tile
#define FPSCALE 4194304.0f     // 2^22 fixed point; capacity 1024 > max sum 488
#define FPINV   (1.0f / 4194304.0f)

// Extract step K's function index from packed nibble words p0..p3.
#define GETIDX(K)                                                              \
    ((int)(((((K) >> 3) == 0 ? p0 : ((K) >> 3) == 1 ? p1                       \
            : ((K) >> 3) == 2 ? p2 : p3) >> (((K) & 7) * 4)) & 7u))

// One chaos-game step, numpy-exact (no FMA contraction). Scalar LDS table
// reads: 8 distinct rows max -> broadcast/2-way aliasing (free on CDNA4).
#define FLAME_STEP(IDX, K)                                                     \
  {                                                                            \
    const float a00 = s_tab[(IDX)*8+0], a01 = s_tab[(IDX)*8+1];                \
    const float a10 = s_tab[(IDX)*8+2], a11 = s_tab[(IDX)*8+3];                \
    const float b0  = s_tab[(IDX)*8+4], b1  = s_tab[(IDX)*8+5];                \
    const float fc  = s_tab[(IDX)*8+6];                                        \
    const float nx = __fadd_rn(__fadd_rn(__fmul_rn(a00,x),__fmul_rn(a01,y)),b0);\
    const float ny = __fadd_rn(__fadd_rn(__fmul_rn(a10,x),__fmul_rn(a11,y)),b1);\
    x = nx; y = ny;                                                            \
    c = __fmul_rn(__fadd_rn(c, fc), 0.5f);                                     \
    xb = (int)__fmul_rn(__fsub_rn(x, minx), rx);                               \
    yb = (int)__fmul_rn(__fsub_rn(y, miny), ry);                               \
    inb = (xb >= 0) & (xb < IMG_W) & (yb >= 0) & (yb < IMG_H) & ((K) >= skipk);\
  }

#define LOAD_TABLES()                                                          \
    if (threadIdx.x < NF) {                                                    \
        const int f = threadIdx.x;                                             \
        s_tab[f*8+0] = Amat[f*4+0]; s_tab[f*8+1] = Amat[f*4+1];                \
        s_tab[f*8+2] = Amat[f*4+2]; s_tab[f*8+3] = Amat[f*4+3];                \
        s_tab[f*8+4] = bvec[f*2+0]; s_tab[f*8+5] = bvec[f*2+1];                \
        s_tab[f*8+6] = fcolor[f];   s_tab[f*8+7] = 0.0f;                       \
    }

__device__ __forceinline__ u32* part_ptr(u32* partA, u32* partB, u32 w) {
    return (w < PARTA_CH) ? partA + (size_t)w * (BKTPX * 4)
                          : partB + (size_t)(w - PARTA_CH) * (BKTPX * 4);
}
__device__ __forceinline__ const u32* part_ptr_c(const u32* partA,
                                                 const u32* partB, u32 w) {
    return (w < PARTA_CH) ? partA + (size_t)w * (BKTPX * 4)
                          : partB + (size_t)(w - PARTA_CH) * (BKTPX * 4);
}

// Wave-level inclusive scan of v across the 64-lane wave (6 shfl steps).
__device__ __forceinline__ u32 wave_incl_scan(u32 v, int lane) {
    #pragma unroll
    for (int o = 1; o < 64; o <<= 1) {
        const u32 n = __shfl_up(v, o);
        if (lane >= o) v += n;
    }
    return v;
}

// ---------------------------------------------------------------------------
// K1: the ONLY flame pass (byte-identical to round-20 champion).
// ---------------------------------------------------------------------------
__global__ __launch_bounds__(256) void k_flame(
    const float* __restrict__ Amat, const float* __restrict__ bvec,
    const float* __restrict__ fcolor,
    const float* __restrict__ xy0, const float* __restrict__ c0,
    const float* __restrict__ minv, const float* __restrict__ rangev,
    const int* __restrict__ fn_idx, const int* __restrict__ skipk_ptr,
    u32* __restrict__ counts, u32* __restrict__ lpre,
    u32* __restrict__ blockmajor)
{
    __shared__ u32 s_rec[SEGW];          // 32 KB
    __shared__ u32 s_cnt[NBKT];          // counts, then cursors
    __shared__ u32 s_wsum[4];
    __shared__ u32 s_vt;
    __shared__ float s_tab[NF * 8];
    const int tid = threadIdx.x;
    const int lane = tid & 63, wav = tid >> 6;

    s_cnt[tid] = 0u; s_cnt[tid + 256] = 0u;
    LOAD_TABLES();
    __syncthreads();

    const int i = blockIdx.x * 256 + tid;
    u32 rec[KSTEPS];

    if (i < NPTS) {
        u32 p0 = 0, p1 = 0, p2 = 0, p3 = 0;
        #pragma unroll
        for (int k = 0; k < 8; ++k)
            p0 |= ((u32)fn_idx[(size_t)k * NPTS + i] & 7u) << (k * 4);
        #pragma unroll
        for (int k = 0; k < 8; ++k)
            p1 |= ((u32)fn_idx[(size_t)(k + 8) * NPTS + i] & 7u) << (k * 4);
        #pragma unroll
        for (int k = 0; k < 8; ++k)
            p2 |= ((u32)fn_idx[(size_t)(k + 16) * NPTS + i] & 7u) << (k * 4);
        #pragma unroll
        for (int k = 0; k < 8; ++k)
            p3 |= ((u32)fn_idx[(size_t)(k + 24) * NPTS + i] & 7u) << (k * 4);

        const int   skipk = skipk_ptr[0];
        const float minx = minv[0], miny = minv[1];
        const float rx = rangev[0], ry = rangev[1];
        const float2 xyv = ((const float2*)xy0)[i];
        float x = xyv.x, y = xyv.y, c = c0[i];
        #pragma unroll
        for (int k = 0; k < KSTEPS; ++k) {
            const int idx = GETIDX(k);
            int xb, yb; bool inb;
            FLAME_STEP(idx, k);
            u32 r = 0xFFFFFFFFu;
            if (inb) {
                int pi = (int)__fadd_rn(__fmul_rn(c, 999.0f), 0.0005f);
                pi = min(max(pi, 0), FID - 1);
                r = (((u32)(xb << 10 | yb)) << 10) | (u32)pi;
                atomicAdd(&s_cnt[r >> 21], 1u);
            }
            rec[k] = r;
        }
    }
    __syncthreads();

    // Shuffle-based exclusive scan over 512 bucket counts (2 per thread).
    const u32 cA = s_cnt[2 * tid], cB = s_cnt[2 * tid + 1];
    const u32 psum = cA + cB;
    u32 v = wave_incl_scan(psum, lane);
    if (lane == 63) s_wsum[wav] = v;
    __syncthreads();
    u32 off = 0;
    #pragma unroll
    for (int wv = 0; wv < 4; ++wv)
        if (wv < wav) off += s_wsum[wv];
    const u32 incl = v + off;
    const u32 excl = incl - psum;

    // Cursors in LDS; per-(block,bucket) meta to global (coalesced).
    s_cnt[2 * tid] = excl; s_cnt[2 * tid + 1] = excl + cA;
    const size_t g0 = (size_t)blockIdx.x * NBKT;
    lpre[g0 + 2 * tid] = excl;  lpre[g0 + 2 * tid + 1] = excl + cA;
    counts[g0 + 2 * tid] = cA;  counts[g0 + 2 * tid + 1] = cB;
    if (tid == 255) s_vt = incl;         // total valid records
    __syncthreads();

    // Re-scatter rec[] from VGPRs into LDS, bucket-sorted.
    if (i < NPTS) {
        #pragma unroll
        for (int k = 0; k < KSTEPS; ++k) {
            const u32 r = rec[k];
            if (r != 0xFFFFFFFFu) {
                const u32 pos = atomicAdd(&s_cnt[r >> 21], 1u);
                s_rec[pos] = r;
            }
        }
    }
    __syncthreads();

    // Dense copy to block-major segment (uint4).
    const u32 vt = s_vt;
    u32* dst = blockmajor + (size_t)blockIdx.x * SEGW;
    const u32 nv4 = vt >> 2;
    for (u32 q = tid; q < nv4; q += 256)
        ((uint4*)dst)[q] = make_uint4(s_rec[4*q], s_rec[4*q+1],
                                      s_rec[4*q+2], s_rec[4*q+3]);
    for (u32 j = (nv4 << 2) + tid; j < vt; j += 256) dst[j] = s_rec[j];
}

// ---------------------------------------------------------------------------
// K2: LDS-TILED transpose (64x64, +1-pad) — coalesced reads AND writes
// (old version read 2KB-strided: 64 lines/wave-load, ~16x line traffic).
// Totals via per-block column partial sums + one atomic wave (totals
// pre-zeroed by hipMemsetAsync).
// ---------------------------------------------------------------------------
__global__ __launch_bounds__(256) void k_transpose(
    const u32* __restrict__ counts, const u32* __restrict__ lpre,
    u32* __restrict__ counts_t, u32* __restrict__ lpre_t,
    u32* __restrict__ totals)
{
    __shared__ u32 tc[TT][TT + 1];
    __shared__ u32 tl[TT][TT + 1];
    __shared__ u32 psum[4][TT];
    const int tx = threadIdx.x & 63, ty = threadIdx.x >> 6;
    const int b0 = blockIdx.x * TT;      // bucket tile (NBKT/TT = 8)
    const int g0 = blockIdx.y * TT;      // block-row tile (ceil(NB/TT) = 62)

    u32 colsum = 0;
    #pragma unroll
    for (int j = 0; j < 16; ++j) {
        const int g = g0 + ty * 16 + j;
        u32 cv = 0, lv = 0;
        if (g < NB) {
            cv = counts[(size_t)g * NBKT + b0 + tx];   // coalesced
            lv = lpre[(size_t)g * NBKT + b0 + tx];     // coalesced
        }
        tc[ty * 16 + j][tx] = cv;
        tl[ty * 16 + j][tx] = lv;
        colsum += cv;
    }
    psum[ty][tx] = colsum;
    __syncthreads();

    if (ty == 0) {
        const u32 s = psum[0][tx] + psum[1][tx] + psum[2][tx] + psum[3][tx];
        if (s) atomicAdd(&totals[b0 + tx], s);
    }

    #pragma unroll
    for (int j = 0; j < 16; ++j) {
        const int b = b0 + ty * 16 + j;
        const int g = g0 + tx;
        if (g < NB) {
            counts_t[(size_t)b * NB + g] = tc[tx][ty * 16 + j];  // coalesced
            lpre_t[(size_t)b * NB + g]   = tl[tx][ty * 16 + j];  // coalesced
        }
    }
}

// ---------------------------------------------------------------------------
// K3: chunk counts m[b], wstart scan, fixed-point palette. 1 wg x 512.
// ---------------------------------------------------------------------------
__global__ __launch_bounds__(512) void k_meta(
    const float* __restrict__ palette,
    const u32* __restrict__ totals,
    u32* __restrict__ mm, u32* __restrict__ wstart,
    u32* __restrict__ pal_u32)
{
    __shared__ u32 sc[NBKT];
    const int tid = threadIdx.x;

    for (int t = tid; t < FID * 4; t += 512)
        pal_u32[t] = __float2uint_rn(__fmul_rn(palette[t], FPSCALE));

    const u32 t0 = totals[tid];
    sc[tid] = t0; __syncthreads();
    #pragma unroll
    for (int o = 1; o < NBKT; o <<= 1) {
        u32 v = (tid >= o) ? sc[tid - o] : 0u;
        __syncthreads(); sc[tid] += v; __syncthreads();
    }
    const u32 total = sc[NBKT - 1];

    const u32 m = 1u + (total ? (u32)((504ull * t0) / total) : 0u);
    mm[tid] = m;
    __syncthreads(); sc[tid] = m; __syncthreads();
    #pragma unroll
    for (int o = 1; o < NBKT; o <<= 1) {
        u32 v = (tid >= o) ? sc[tid - o] : 0u;
        __syncthreads(); sc[tid] += v; __syncthreads();
    }
    wstart[tid] = sc[tid] - m;
    if (tid == NBKT - 1) wstart[NBKT] = sc[NBKT - 1];
}

// ---------------------------------------------------------------------------
// K4 v10: round-16 v6 walk + shuffle scan (byte-identical to round-20).
// ---------------------------------------------------------------------------
__global__ __launch_bounds__(512) void k_accum(
    const u32* __restrict__ pal_u32,
    const u32* __restrict__ counts_t, const u32* __restrict__ lpre_t,
    const u32* __restrict__ mm, const u32* __restrict__ wstart,
    const u32* __restrict__ blockmajor,
    u32* __restrict__ partA, u32* __restrict__ partB)
{
    __shared__ u64 tileA[BKTPX];        // ch0|ch1 (16 KB)
    __shared__ u64 tileB[BKTPX];        // ch2|ch3 (16 KB)
    __shared__ u32 s_ml[MSTG];          // staged lp (2 KB)
    __shared__ u32 s_pfx[MSTG + 1];     // run starts
    __shared__ u32 s_ws[NBKT + 1];
    __shared__ u32 s_wsum[8];
    const int tid = threadIdx.x, w = blockIdx.x;
    const int lane = tid & 63, wav = tid >> 6;

    if (tid < NBKT) s_ws[tid] = wstart[tid];
    if (tid == 0)   s_ws[NBKT] = wstart[NBKT];
    __syncthreads();
    if ((u32)w >= s_ws[NBKT]) return;   // uniform per block

    int b = 0;
    #pragma unroll
    for (int step = 256; step; step >>= 1)
        if (b + step <= NBKT - 1 && s_ws[b + step] <= (u32)w) b += step;

    for (int t = tid; t < BKTPX; t += 512) { tileA[t] = 0ull; tileB[t] = 0ull; }

    const u32 m = mm[b], cch = (u32)w - s_ws[b];
    const u32 gs = (u32)(((u64)NB * cch) / m);
    const u32 ge = (u32)(((u64)NB * (cch + 1)) / m);

    const uint4* pal4 = (const uint4*)pal_u32;
    const u32* ct = counts_t + (size_t)b * NB;
    const u32* lt = lpre_t + (size_t)b * NB;

    for (u32 g0 = gs; g0 < ge; g0 += MSTG) {
        const u32 nm = min((u32)MSTG, ge - g0);
        __syncthreads();                 // protect prior stage's readers
        const u32 myc = (tid < (int)nm) ? ct[g0 + tid] : 0u;   // coalesced
        if (tid < (int)nm) s_ml[tid] = lt[g0 + tid];           // coalesced

        // Shuffle-based inclusive scan of myc over 512 threads (2 barriers).
        u32 v = wave_incl_scan(myc, lane);
        if (lane == 63) s_wsum[wav] = v;
        __syncthreads();
        u32 off = 0;
        #pragma unroll
        for (int wv = 0; wv < 8; ++wv)
            if (wv < wav) off += s_wsum[wv];
        s_pfx[tid + 1] = v + off;        // inclusive
        if (tid == 0) s_pfx[0] = 0u;
        __syncthreads();
        const u32 R = s_pfx[MSTG];       // records in this stage

        // Flat, balanced walk with one-ahead pipeline (v6 structure).
        u32 idx = (u32)tid;
        u32 r_c = 0;
        if (idx < R) {
            u32 g = 0;
            #pragma unroll
            for (int step = 256; step; step >>= 1)
                if (s_pfx[g + step] <= idx) g += step;
            r_c = blockmajor[(size_t)(g0 + g) * SEGW + s_ml[g] +
                             (idx - s_pfx[g])];
        }
        while (idx < R) {
            const u32 nidx = idx + 512;
            u32 r_n = 0;
            if (nidx < R) {
                u32 g = 0;
                #pragma unroll
                for (int step = 256; step; step >>= 1)
                    if (s_pfx[g + step] <= nidx) g += step;
                r_n = blockmajor[(size_t)(g0 + g) * SEGW + s_ml[g] +
                                 (nidx - s_pfx[g])];   // prefetch next
            }
            const uint4 pc = pal4[r_c & 1023u];        // one palette load
            const u32 local = (r_c >> 10) & (BKTPX - 1);
            atomicAdd(&tileA[local], (u64)pc.x | ((u64)pc.y << 32));
            atomicAdd(&tileB[local], (u64)pc.z | ((u64)pc.w << 32));
            idx = nidx; r_c = r_n;
        }
    }
    __syncthreads();

    uint4* dst = (uint4*)part_ptr(partA, partB, (u32)w);
    for (int t = tid; t < BKTPX; t += 512)
        dst[t] = make_uint4((u32)tileA[t], (u32)(tileA[t] >> 32),
                            (u32)tileB[t], (u32)(tileB[t] >> 32));
}

// ---------------------------------------------------------------------------
// K5: sum partial tiles per bucket, unpack, add raw_image, write CHW out.
// ---------------------------------------------------------------------------
__global__ __launch_bounds__(256) void k_final(
    const u32* __restrict__ partA, const u32* __restrict__ partB,
    const u32* __restrict__ wstart,
    const float* __restrict__ raw, float* __restrict__ out)
{
    const int p = blockIdx.x * 256 + threadIdx.x;
    const int b = p >> 11, local = p & (BKTPX - 1);
    u32 a0 = 0, a1 = 0, a2 = 0, a3 = 0;
    const u32 w0 = wstart[b], w1 = wstart[b + 1];
    for (u32 w = w0; w < w1; ++w) {
        const uint4 v = ((const uint4*)part_ptr_c(partA, partB, w))[local];
        a0 += v.x; a1 += v.y; a2 += v.z; a3 += v.w;
    }
    out[0*(size_t)HW + p] = __fadd_rn(raw[0*(size_t)HW + p], __fmul_rn((float)a0, FPINV));
    out[1*(size_t)HW + p] = __fadd_rn(raw[1*(size_t)HW + p], __fmul_rn((float)a1, FPINV));
    out[2*(size_t)HW + p] = __fadd_rn(raw[2*(size_t)HW + p], __fmul_rn((float)a2, FPINV));
    out[3*(size_t)HW + p] = __fadd_rn(raw[3*(size_t)HW + p], __fmul_rn((float)a3, FPINV));
}

// ---------------------------------------------------------------------------
// Fallback (ws too small): packed u64 global atomics (round-3 path).
// ---------------------------------------------------------------------------
__global__ __launch_bounds__(256) void flame_accum_packed(
    const float* __restrict__ palette,
    const float* __restrict__ Amat, const float* __restrict__ bvec,
    const float* __restrict__ fcolor,
    const float* __restrict__ xy0, const float* __restrict__ c0,
    const float* __restrict__ minv, const float* __restrict__ rangev,
    const int* __restrict__ fn_idx, const int* __restrict__ skipk_ptr,
    u64* __restrict__ ws)
{
    __shared__ __align__(16) float s_pal[FID * 4];
    __shared__ float s_tab[NF * 8];
    for (int t = threadIdx.x; t < FID; t += 256)
        ((float4*)s_pal)[t] = ((const float4*)palette)[t];
    LOAD_TABLES();
    __syncthreads();

    const int i = blockIdx.x * 256 + threadIdx.x;
    if (i >= NPTS) return;
    const int   skipk = skipk_ptr[0];
    const float minx = minv[0], miny = minv[1];
    const float rx = rangev[0], ry = rangev[1];
    const float2 xyv = ((const float2*)xy0)[i];
    float x = xyv.x, y = xyv.y, c = c0[i];
    for (int k = 0; k < KSTEPS; ++k) {
        const int idx = fn_idx[(size_t)k * NPTS + i];
        int xb, yb; bool inb;
        FLAME_STEP(idx, k);
        if (inb) {
            int pi = (int)__fadd_rn(__fmul_rn(c, 999.0f), 0.0005f);
            pi = min(max(pi, 0), FID - 1);
            const float4 col = *(const float4*)&s_pal[pi * 4];
            const u32 u0 = __float2uint_rn(__fmul_rn(col.x, FPSCALE));
            const u32 u1 = __float2uint_rn(__fmul_rn(col.y, FPSCALE));
            const u32 u2 = __float2uint_rn(__fmul_rn(col.z, FPSCALE));
            const u32 u3 = __float2uint_rn(__fmul_rn(col.w, FPSCALE));
            u64* p = ws + ((size_t)xb * IMG_W + yb) * 2;
            atomicAdd(p + 0, (u64)u0 | ((u64)u1 << 32));
            atomicAdd(p + 1, (u64)u2 | ((u64)u3 << 32));
        }
    }
}

__global__ __launch_bounds__(256) void reduce_packed(
    const u64* __restrict__ ws, const float* __restrict__ raw_image,
    float* __restrict__ out)
{
    const int p = blockIdx.x * 256 + threadIdx.x;
    if (p >= HW) return;
    const u64 w0 = ws[(size_t)p * 2 + 0];
    const u64 w1 = ws[(size_t)p * 2 + 1];
    out[0*(size_t)HW+p] = raw_image[0*(size_t)HW+p] + (float)(u32)(w0 & 0xffffffffull) * FPINV;
    out[1*(size_t)HW+p] = raw_image[1*(size_t)HW+p] + (float)(u32)(w0 >> 32)           * FPINV;
    out[2*(size_t)HW+p] = raw_image[2*(size_t)HW+p] + (float)(u32)(w1 & 0xffffffffull) * FPINV;
    out[3*(size_t)HW+p] = raw_image[3*(size_t)HW+p] + (float)(u32)(w1 >> 32)           * FPINV;
}

extern "C" void kernel_launch(void* const* d_in, const int* in_sizes, int n_in,
                              void* d_out, int out_size, void* d_ws, size_t ws_size,
                              hipStream_t stream) {
    const float* raw_image = (const float*)d_in[0];
    const float* palette   = (const float*)d_in[1];
    const float* A         = (const float*)d_in[2];
    const float* b         = (const float*)d_in[3];
    const float* fcolor    = (const float*)d_in[4];
    const float* xy0       = (const float*)d_in[5];
    const float* c0        = (const float*)d_in[6];
    const float* minv      = (const float*)d_in[7];
    const float* rangev    = (const float*)d_in[8];
    const int*   fn_idx    = (const int*)d_in[9];
    const int*   skipk     = (const int*)d_in[10];
    float* img = (float*)d_out;

    // ws layout (u32 units). counts+lpre (16 MB) are dead after k_transpose,
    // so the first PARTA_CH partial tiles alias them (partA); the remaining
    // tiles live in partB after blockmajor.
    u32* ws = (u32*)d_ws;
    const size_t NBG = (size_t)NB * NBKT;                  // 2,000,384
    u32* counts     = ws;                                  // NBG
    u32* lpre       = counts + NBG;                        // NBG
    u32* counts_t   = lpre + NBG;                          // NBG
    u32* lpre_t     = counts_t + NBG;                      // NBG
    u32* totals     = lpre_t + NBG;                        // 512
    u32* mm         = totals + NBKT;                       // 512
    u32* wstart     = mm + NBKT;                           // 513 (pad 1024)
    u32* pal_u32    = wstart + 1024;                       // 4096
    u32* blockmajor = pal_u32 + 4096;                      // NB*SEGW (128MB)
    u32* partB      = blockmajor + (size_t)NB * SEGW;      // (PARTCH-488)*8192
    u32* partA      = counts;                              // aliased
    const size_t need_u32 = (size_t)(partB - ws) +
                            (size_t)(PARTCH - PARTA_CH) * (BKTPX * 4);
    const size_t NEED = need_u32 * sizeof(u32);            // ~177.36 MB

    if (ws_size >= NEED) {
        hipMemsetAsync(totals, 0, NBKT * sizeof(u32), stream);
        k_flame<<<dim3(NB), 256, 0, stream>>>(A, b, fcolor, xy0, c0, minv,
                                              rangev, fn_idx, skipk,
                                              counts, lpre, blockmajor);
        k_transpose<<<dim3(NBKT / TT, (NB + TT - 1) / TT), 256, 0, stream>>>(
            counts, lpre, counts_t, lpre_t, totals);
        k_meta<<<dim3(1), 512, 0, stream>>>(palette, totals, mm, wstart,
                                            pal_u32);
        k_accum<<<dim3(K5G), 512, 0, stream>>>(pal_u32, counts_t, lpre_t, mm,
                                               wstart, blockmajor,
                                               partA, partB);
        k_final<<<dim3(HW / 256), 256, 0, stream>>>(partA, partB, wstart,
                                                    raw_image, img);
    } else {
        const size_t need2 = (size_t)HW * 2 * sizeof(u64);
        hipMemsetAsync(d_ws, 0, need2, stream);
        flame_accum_packed<<<dim3(NB), 256, 0, stream>>>(
            palette, A, b, fcolor, xy0, c0, minv, rangev, fn_idx, skipk,
            (u64*)d_ws);
        reduce_packed<<<dim3((HW + 255) / 256), 256, 0, stream>>>(
            (const u64*)d_ws, raw_image, img);
    }
}